// Round 2
// baseline (199.784 us; speedup 1.0000x reference)
//
#include <hip/hip_runtime.h>

// LocalConv: out[b][o][oh][ow] = sum_f patch[p][b][f] * W[p][f][o]
// B=64, C=16, H=W=64, K=3x3, OH=OW=62, OUT_CH=32, FEAT=144, P=3844
// Block = (oh, ow-tile of 16, batch-half of 32). Register acc per position,
// coalesced 64B-per-lane output writes along ow.
#define CIN   16
#define HH    64
#define WW    64
#define OHD   62
#define OWD   62
#define OUTC  32
#define FEATN 144
#define KPAD  160   // FEAT padded to 5 K-chunks of 32
#define LSTR  168   // LDS row stride (bf16): 336B, 16B-multiple, 2-way-bank-free
#define MB    32    // batches per block (batch half)

typedef __attribute__((ext_vector_type(8))) short  short8;
typedef __attribute__((ext_vector_type(4))) float  f32x4;
typedef __attribute__((ext_vector_type(2))) float  f32x2;

__device__ __forceinline__ unsigned short f2bf(float f) {
    unsigned int u = __float_as_uint(f);
    u += 0x7FFFu + ((u >> 16) & 1u);   // RNE
    return (unsigned short)(u >> 16);
}

template<int TWQ>
__device__ __forceinline__ void conv_body(
    const float* __restrict__ inp,   // [64][16][64][64]
    const float* __restrict__ wgt,   // [P][144][32]
    float* __restrict__ out,         // [64][32][62][62]
    int oh, int ow0, int bh,
    unsigned short* A_lds,           // [MB][LSTR]
    unsigned short* B_lds)           // [OUTC][LSTR]
{
    const int tid = threadIdx.x;

    // zero-pad K range [144,160) once (stage loops never touch it)
    for (int i = tid; i < MB * (KPAD - FEATN); i += 256)
        A_lds[(i >> 4) * LSTR + FEATN + (i & 15)] = 0;
    for (int i = tid; i < OUTC * (KPAD - FEATN); i += 256)
        B_lds[(i >> 4) * LSTR + FEATN + (i & 15)] = 0;

    const int wid  = tid >> 6;
    const int lane = tid & 63;
    const int fr   = lane & 15;    // frag row/col
    const int fq   = lane >> 4;    // frag k-quad
    const int mt   = wid >> 1;     // m-tile (16 batches)
    const int nt   = wid & 1;      // n-tile (16 out ch)

    f32x4 acc[TWQ];
    #pragma unroll
    for (int q = 0; q < TWQ; ++q) acc[q] = (f32x4){0.f, 0.f, 0.f, 0.f};

    // A staging: thread handles (bl0,c0) and (bl0+16,c0)
    const int bl0 = tid >> 4;      // 0..15
    const int c0  = tid & 15;      // 0..15

    #pragma unroll
    for (int q = 0; q < TWQ; ++q) {
        const int ow = ow0 + q;
        const int p  = oh * OWD + ow;

        // ---- stage W_p: [144][32] fp32 -> B_lds[o][f] bf16 (coalesced float4)
        {
            const f32x4* w4 = (const f32x4*)(wgt + (size_t)p * (FEATN * OUTC));
            #pragma unroll
            for (int it = 0; it < 5; ++it) {
                int idx = tid + it * 256;
                if (idx < (FEATN * OUTC / 4)) {
                    f32x4 v = w4[idx];
                    int f  = idx >> 3;
                    int o0 = (idx & 7) << 2;
                    B_lds[(o0 + 0) * LSTR + f] = f2bf(v[0]);
                    B_lds[(o0 + 1) * LSTR + f] = f2bf(v[1]);
                    B_lds[(o0 + 2) * LSTR + f] = f2bf(v[2]);
                    B_lds[(o0 + 3) * LSTR + f] = f2bf(v[3]);
                }
            }
        }

        // ---- stage A patches (2 (b,c) pairs per thread, 9 scalars each)
        #pragma unroll
        for (int h = 0; h < 2; ++h) {
            int bl = bl0 + h * 16;
            int bg = bh * MB + bl;
            const float* src = inp + (((size_t)(bg * CIN + c0) * HH + oh) * WW + ow);
            unsigned short* dst = &A_lds[bl * LSTR + c0 * 9];
            #pragma unroll
            for (int kh = 0; kh < 3; ++kh) {
                float v0 = src[kh * WW + 0];
                float v1 = src[kh * WW + 1];
                float v2 = src[kh * WW + 2];
                dst[kh * 3 + 0] = f2bf(v0);
                dst[kh * 3 + 1] = f2bf(v1);
                dst[kh * 3 + 2] = f2bf(v2);
            }
        }

        __syncthreads();

        // ---- MFMA: wave's 16x16 tile, 5 K-chunks
        #pragma unroll
        for (int kc = 0; kc < 5; ++kc) {
            const int koff = kc * 32 + fq * 8;
            short8 a = *(const short8*)&A_lds[(mt * 16 + fr) * LSTR + koff];
            short8 b = *(const short8*)&B_lds[(nt * 16 + fr) * LSTR + koff];
            acc[q] = __builtin_amdgcn_mfma_f32_16x16x32_bf16(a, b, acc[q], 0, 0, 0);
        }

        __syncthreads();   // before next position's staging overwrites LDS
    }

    // ---- write: lane owns (b = bh*32+mt*16+fq*4+r, o = nt*16+fr),
    // TWQ consecutive floats along ow (always 8B-aligned -> float2 stores)
    const int o = nt * 16 + fr;
    const int bbase = bh * MB + mt * 16 + fq * 4;
    #pragma unroll
    for (int r = 0; r < 4; ++r) {
        float* dst = out + ((size_t)((bbase + r) * OUTC + o)) * (size_t)(OHD * OWD)
                     + (size_t)oh * OWD + ow0;
        #pragma unroll
        for (int qq = 0; qq < TWQ / 2; ++qq) {
            f32x2 v = { acc[2 * qq][r], acc[2 * qq + 1][r] };
            *(f32x2*)(dst + 2 * qq) = v;
        }
    }
}

__global__ __launch_bounds__(256) void localconv_kernel(
    const float* __restrict__ inp,
    const float* __restrict__ wgt,
    float* __restrict__ out)
{
    __shared__ unsigned short A_lds[MB * LSTR];
    __shared__ unsigned short B_lds[OUTC * LSTR];

    // XCD-pairing swizzle: the two batch-halves of one (oh,owt) land on the
    // same XCD in adjacent slots (assumes round-robin wg->XCD; locality-only).
    const int raw = blockIdx.x;          // [0,496)
    const int xcd = raw & 7;
    const int s   = raw >> 3;            // [0,62)
    const int bh  = s & 1;
    const int g   = (s >> 1) * 8 + xcd;  // [0,248) bijective
    const int oh  = g >> 2;
    const int owt = g & 3;
    const int ow0 = owt * 16;

    if (owt < 3)
        conv_body<16>(inp, wgt, out, oh, ow0, bh, A_lds, B_lds);
    else
        conv_body<14>(inp, wgt, out, oh, ow0, bh, A_lds, B_lds);
}

extern "C" void kernel_launch(void* const* d_in, const int* in_sizes, int n_in,
                              void* d_out, int out_size, void* d_ws, size_t ws_size,
                              hipStream_t stream) {
    const float* inp = (const float*)d_in[0];
    const float* wgt = (const float*)d_in[1];
    float* out = (float*)d_out;
    localconv_kernel<<<dim3(496), 256, 0, stream>>>(inp, wgt, out);
}

// Round 3
// 39.443 us; speedup vs baseline: 5.0652x; 5.0652x over previous
//
#include <hip/hip_runtime.h>

// LocalConv: out[b][o][oh][ow] = sum_f inp-patch[p][b][f] * W[p][f][o]
// B=64, C=16, H=W=64, K=3x3, OH=OW=62, OUT_CH=32, FEAT=144, P=3844
//
// Block = (oh, 16-wide ow strip) x ALL 64 batches x 32 outch. 512 thr, 8 waves.
// Weights: fetched exactly once (71 MB floor), double-buffered pipeline.
// Input: staged ONCE per block as Araw[kh][w][b][c] (K permuted to
// f'' = (kh*3+kw)*16 + c) so A-fragments are direct ds_read_b128 at w=q+kw.
#define CIN    16
#define HH     64
#define WW     64
#define OHD    62
#define OWD    62
#define OUTC   32
#define FEATN  144
#define POUT   (OHD*OWD)
#define LSTRB  168                    // B row stride (bf16): K=160 pad + 8
#define AR_W   18                     // Araw w-dim (max TW+2)
#define AR_ELEMS   (3*AR_W*64*16)     // 55296
#define BBUF_ELEMS (OUTC*LSTRB)       // 5376
#define SMEM_BYTES ((AR_ELEMS + 2*BBUF_ELEMS)*2)   // 132096 B

typedef __attribute__((ext_vector_type(8))) short  short8;
typedef __attribute__((ext_vector_type(4))) float  f32x4;
typedef __attribute__((ext_vector_type(2))) float  f32x2;

__device__ __forceinline__ unsigned short f2bf(float f) {
    unsigned int u = __float_as_uint(f);
    u += 0x7FFFu + ((u >> 16) & 1u);   // RNE
    return (unsigned short)(u >> 16);
}

// write one float4 of W[p] (orig f = c*9 + kh*3 + kw, o0..o0+3) to B_lds[o][f'']
__device__ __forceinline__ void storeB4(unsigned short* Bb, int idx, f32x4 v) {
    int f   = idx >> 3;
    int o0  = (idx & 7) << 2;
    int c   = (f * 57) >> 9;       // f/9 for f<144
    int g   = f - 9 * c;           // kh*3+kw
    int fpp = g * 16 + c;          // permuted K index
    Bb[(o0 + 0) * LSTRB + fpp] = f2bf(v[0]);
    Bb[(o0 + 1) * LSTRB + fpp] = f2bf(v[1]);
    Bb[(o0 + 2) * LSTRB + fpp] = f2bf(v[2]);
    Bb[(o0 + 3) * LSTRB + fpp] = f2bf(v[3]);
}

template<int TW>
__device__ __forceinline__ void conv_body(
    const float* __restrict__ inp, const float* __restrict__ wgt,
    float* __restrict__ out, int oh, int ow0,
    unsigned short* __restrict__ Araw, unsigned short* __restrict__ B_lds)
{
    const int tid = threadIdx.x;
    constexpr int WTOT = TW + 2;

    // ---- stage A slab once: Araw[kh][w][b][c] = bf16(inp[b][c][oh+kh][ow0+w])
    //      c-half XOR-swizzled by (b>>2)&1 (granule bank spread for frag reads)
    for (int t = tid; t < 3 * 64 * WTOT; t += 512) {
        int w   = t % WTOT;
        int rem = t / WTOT;
        int b   = rem & 63;
        int kh  = rem >> 6;
        const float* src = inp + (size_t)b * (CIN * HH * WW)
                               + (size_t)(oh + kh) * WW + (ow0 + w);
        short8 h0, h1;
        #pragma unroll
        for (int c = 0; c < 8; ++c) h0[c] = (short)f2bf(src[(size_t)c * (HH * WW)]);
        #pragma unroll
        for (int c = 0; c < 8; ++c) h1[c] = (short)f2bf(src[(size_t)(c + 8) * (HH * WW)]);
        int s = (b >> 2) & 1;
        unsigned short* dst = Araw + ((kh * AR_W + w) * 64 + b) * 16;
        *(short8*)(dst + s * 8)       = h0;   // elements c0..7 at granule s
        *(short8*)(dst + (1 - s) * 8) = h1;   // elements c8..15 at granule 1-s
    }

    // ---- zero B pad k'' in [144,160), both buffers (A pad is reg-zeroed;
    //      both sides zero so pad contributes exact 0, never 0*NaN)
    for (int t = tid; t < 2 * OUTC * 16; t += 512) {
        int buf = t >> 9;
        int o   = (t >> 4) & 31;
        B_lds[buf * BBUF_ELEMS + o * LSTRB + 144 + (t & 15)] = 0;
    }

    // ---- weight pipeline registers (3 float4/thread covers 1152 float4)
    const int p0 = oh * OWD + ow0;
    f32x4 wr0, wr1, wr2;
    auto issue = [&](int q) {
        const f32x4* src = (const f32x4*)(wgt + (size_t)(p0 + q) * (FEATN * OUTC));
        wr0 = src[tid];
        wr1 = src[512 + tid];
        if (tid < 128) wr2 = src[1024 + tid];
    };
    auto writeB = [&](unsigned short* Bb) {
        storeB4(Bb, tid, wr0);
        storeB4(Bb, 512 + tid, wr1);
        if (tid < 128) storeB4(Bb, 1024 + tid, wr2);
    };

    // ---- per-thread fragment addressing
    const int wid = tid >> 6, lane = tid & 63;
    const int fr  = lane & 15, fq = lane >> 4, fqh = fq >> 1;
    const int mt  = wid >> 1, nt = wid & 1;          // 4 m-tiles x 2 n-tiles
    const int b   = mt * 16 + fr;                    // A row = batch
    const int c0e = (((fq & 1) ^ ((b >> 2) & 1)) << 3);  // swizzled c-half
    int abase[5], boff[5];
    #pragma unroll
    for (int kc = 0; kc < 5; ++kc) {
        int g  = 2 * kc + fqh;                 // (kh*3+kw) group; g==9 -> pad
        int kh = (g * 11) >> 5;
        int kw = g - 3 * kh;
        abase[kc] = ((kh * AR_W + kw) * 64 + b) * 16 + c0e;   // + q*1024/pos
        boff[kc]  = (nt * 16 + fr) * LSTRB + kc * 32 + fq * 8;
    }

    // ---- prologue: one barrier covers Araw + B pads + B[0]
    issue(0);
    writeB(B_lds);          // buf 0 <- q0 (vmcnt wait via reg dep)
    issue(1);
    __syncthreads();

    f32x4 acc[TW];
    #pragma unroll
    for (int q = 0; q < TW; ++q) acc[q] = (f32x4){0.f, 0.f, 0.f, 0.f};

    // ---- main loop: MFMA(q) | writeB(q+1) | barrier | issue(q+2)
    #pragma unroll
    for (int q = 0; q < TW; ++q) {
        const unsigned short* Bc = B_lds + (q & 1) * BBUF_ELEMS;
        #pragma unroll
        for (int kc = 0; kc < 5; ++kc) {
            short8 a;
            if (kc == 4 && fqh == 1)
                a = (short8){0, 0, 0, 0, 0, 0, 0, 0};     // K pad [144,160)
            else
                a = *(const short8*)(Araw + abase[kc] + q * 1024);
            short8 bfr = *(const short8*)(Bc + boff[kc]);
            acc[q] = __builtin_amdgcn_mfma_f32_16x16x32_bf16(a, bfr, acc[q], 0, 0, 0);
        }
        if (q + 1 < TW) writeB(B_lds + ((q + 1) & 1) * BBUF_ELEMS);
        __syncthreads();
        if (q + 2 < TW) issue(q + 2);
    }

    // ---- epilogue: lane owns (b_out = mt*16+fq*4+r, o = nt*16+fr),
    //      TW consecutive floats along ow (8B-aligned f32x2 stores)
    const int o = nt * 16 + fr;
    #pragma unroll
    for (int r = 0; r < 4; ++r) {
        float* dst = out + ((size_t)((mt * 16 + fq * 4 + r) * OUTC + o)) * POUT
                         + (size_t)oh * OWD + ow0;
        #pragma unroll
        for (int j = 0; j < TW / 2; ++j) {
            f32x2 v = { acc[2 * j][r], acc[2 * j + 1][r] };
            *(f32x2*)(dst + 2 * j) = v;
        }
    }
}

__global__ __launch_bounds__(512) void localconv_kernel(
    const float* __restrict__ inp,
    const float* __restrict__ wgt,
    float* __restrict__ out)
{
    extern __shared__ unsigned short smem[];
    unsigned short* Araw  = smem;
    unsigned short* B_lds = smem + AR_ELEMS;

    // chunked XCD swizzle: XCD x gets contiguous work range [31x, 31x+31)
    // -> contiguous oh span per XCD -> input slab ~2.6 MB fits 4 MB L2
    const int l   = (blockIdx.x & 7) * 31 + (blockIdx.x >> 3);   // 248 = 8*31
    const int oh  = l >> 2;
    const int owt = l & 3;

    if (owt < 3) conv_body<16>(inp, wgt, out, oh, owt * 16, Araw, B_lds);
    else         conv_body<14>(inp, wgt, out, oh, 48, Araw, B_lds);
}

extern "C" void kernel_launch(void* const* d_in, const int* in_sizes, int n_in,
                              void* d_out, int out_size, void* d_ws, size_t ws_size,
                              hipStream_t stream) {
    const float* inp = (const float*)d_in[0];
    const float* wgt = (const float*)d_in[1];
    float* out = (float*)d_out;
    hipFuncSetAttribute((const void*)localconv_kernel,
                        hipFuncAttributeMaxDynamicSharedMemorySize, SMEM_BYTES);
    localconv_kernel<<<dim3(62 * 4), 512, SMEM_BYTES, stream>>>(inp, wgt, out);
}

// Round 4
// 37.575 us; speedup vs baseline: 5.3170x; 1.0497x over previous
//
#include <hip/hip_runtime.h>

// LocalConv: out[b][o][oh][ow] = sum_f patch[p][b][f] * W[p][f][o]
// B=64, C=16, H=W=64, K=3x3, OH=OW=62, OUT_CH=32, FEAT=144, P=3844
// Block = (oh, 8-wide ow strip) x 64 batches x 32 outch. 512 thr, 8 waves.
// 80928 B LDS -> 2 blocks/CU. K permuted: f'' = (kh*3+kw)*16 + c.
// B staged via coalesced scalar gathers + conflict-free ds_write_b128.
#define CIN    16
#define HH     64
#define WW     64
#define OHD    62
#define OWD    62
#define OUTC   32
#define FEATN  144
#define POUT   (OHD*OWD)
#define LSTRB  152                      // B row stride: 144 real + 8 zero pad
#define AR_W   10                       // A slab w-dim (max TW+2)
#define AR_ELEMS   (3*AR_W*64*16)       // 30720
#define BBUF_ELEMS (OUTC*LSTRB + 8)     // 4872 (last 8 = zero guard)
#define SMEM_BYTES ((AR_ELEMS + 2*BBUF_ELEMS)*2)   // 80928

typedef __attribute__((ext_vector_type(8))) short  short8;
typedef __attribute__((ext_vector_type(4))) float  f32x4;
typedef __attribute__((ext_vector_type(2))) float  f32x2;

__device__ __forceinline__ unsigned short f2bf(float f) {
    unsigned int u = __float_as_uint(f);
    u += 0x7FFFu + ((u >> 16) & 1u);   // RNE
    return (unsigned short)(u >> 16);
}

template<int TW>
__device__ __forceinline__ void conv_body(
    const float* __restrict__ inp, const float* __restrict__ wgt,
    float* __restrict__ out, int oh, int ow0,
    unsigned short* __restrict__ Araw, unsigned short* __restrict__ B_lds)
{
    const int tid = threadIdx.x;
    constexpr int WTOT = TW + 2;

    // ---- stage A slab: Araw granule G = ((kh*AR_W+w)*64+b)*2 + gr, swizzled
    //      gr = half ^ ((b>>2)&1), G ^= (w&3)<<1  (spreads w-direction banks)
    for (int t = tid; t < 3 * WTOT * 64; t += 512) {
        int w   = t % WTOT;
        int rem = t / WTOT;
        int b   = rem & 63;
        int kh  = rem >> 6;
        const float* src = inp + (size_t)b * (CIN * HH * WW)
                               + (size_t)(oh + kh) * WW + (ow0 + w);
        short8 h0, h1;
        #pragma unroll
        for (int c = 0; c < 8; ++c) h0[c] = (short)f2bf(src[c * (HH * WW)]);
        #pragma unroll
        for (int c = 0; c < 8; ++c) h1[c] = (short)f2bf(src[(c + 8) * (HH * WW)]);
        int s = (b >> 2) & 1;
        unsigned Gb = (unsigned)(((kh * AR_W + w) * 64 + b) * 2);
        unsigned wx = (unsigned)((w & 3) << 1);
        *(short8*)(Araw + (((Gb + s) ^ wx) << 3))       = h0;
        *(short8*)(Araw + (((Gb + (1 - s)) ^ wx) << 3)) = h1;
    }

    // ---- zero B pad [144,152) per row + 8-elem guard per buffer
    for (int t = tid; t < 2 * 264; t += 512) {
        int buf = t / 264, r = t % 264;
        int e = (r < 256) ? ((r >> 3) * LSTRB + 144 + (r & 7))
                          : (OUTC * LSTRB + (r & 7));
        B_lds[buf * BBUF_ELEMS + e] = 0;
    }

    // ---- weight pipeline: thread -> (o=tid&31, pair=tid>>5 -> g=pair>>1, h=pair&1)
    //      covers g=0..7; g=8 handled by tid<64 (h2=(tid>>5)&1).
    //      8 coalesced scalar loads (f = (h*8+j)*9 + g) -> 1 ds_write_b128.
    const int o_w   = tid & 31;
    const int g_w   = (tid >> 6);          // pair>>1 = tid>>6  (0..7)
    const int h_w   = (tid >> 5) & 1;
    const int gbase  = (h_w * 72 + g_w) * 32 + o_w;
    const int gbase2 = ((((tid >> 5) & 1) * 72 + 8) * 32) + o_w;
    const int woff   = o_w * LSTRB + g_w * 16 + h_w * 8;
    const int woff2  = o_w * LSTRB + 128 + ((tid >> 5) & 1) * 8;
    const int p0 = oh * OWD + ow0;

    float wv[8], wv2[8];
    auto issue = [&](int q) {
        const float* wp = wgt + (size_t)(p0 + q) * (FEATN * OUTC);
        #pragma unroll
        for (int j = 0; j < 8; ++j) wv[j] = wp[gbase + j * 288];
        if (tid < 64) {
            #pragma unroll
            for (int j = 0; j < 8; ++j) wv2[j] = wp[gbase2 + j * 288];
        }
    };
    auto writeB = [&](unsigned short* Bb) {
        short8 sv;
        #pragma unroll
        for (int j = 0; j < 8; ++j) sv[j] = (short)f2bf(wv[j]);
        *(short8*)(Bb + woff) = sv;
        if (tid < 64) {
            short8 sv2;
            #pragma unroll
            for (int j = 0; j < 8; ++j) sv2[j] = (short)f2bf(wv2[j]);
            *(short8*)(Bb + woff2) = sv2;
        }
    };

    // ---- fragment addressing
    const int wid = tid >> 6, lane = tid & 63;
    const int fr = lane & 15, fq = lane >> 4, fqh = fq >> 1;
    const int mt = wid >> 1, nt = wid & 1;           // 4 m-tiles x 2 n-tiles
    const int b  = mt * 16 + fr;
    const int gr = (fq & 1) ^ ((b >> 2) & 1);
    unsigned abase_g[5]; int kwv[5]; int boff[5];
    #pragma unroll
    for (int kc = 0; kc < 5; ++kc) {
        int g  = 2 * kc + fqh;                 // 9 -> pad (zero A-frag)
        int gc = (g > 8) ? 8 : g;
        int kh = (gc * 11) >> 5;               // gc/3
        int kw = gc - 3 * kh;
        abase_g[kc] = (unsigned)(((kh * AR_W + kw) * 64 + b) * 2 + gr);
        kwv[kc]     = kw;
        boff[kc]    = (nt * 16 + fr) * LSTRB + kc * 32 + fq * 8;
    }

    // ---- prologue
    issue(0);
    writeB(B_lds);           // buf0 <- q0
    issue(1);
    __syncthreads();

    f32x4 acc[TW];
    #pragma unroll
    for (int q = 0; q < TW; ++q) acc[q] = (f32x4){0.f, 0.f, 0.f, 0.f};

    // ---- main loop: MFMA(q) | writeB(q+1) | barrier | issue(q+2)
    #pragma unroll
    for (int q = 0; q < TW; ++q) {
        const unsigned short* Bc = B_lds + (q & 1) * BBUF_ELEMS;
        #pragma unroll
        for (int kc = 0; kc < 5; ++kc) {
            short8 a;
            if (kc == 4 && fqh == 1) {
                a = (short8){0, 0, 0, 0, 0, 0, 0, 0};   // K in [144,160): A=0
            } else {
                unsigned gi = (abase_g[kc] + (unsigned)(q * 128))
                              ^ (unsigned)(((q + kwv[kc]) & 3) << 1);
                a = *(const short8*)(Araw + (gi << 3));
            }
            short8 bfv = *(const short8*)(Bc + boff[kc]);
            acc[q] = __builtin_amdgcn_mfma_f32_16x16x32_bf16(a, bfv, acc[q], 0, 0, 0);
        }
        if (q + 1 < TW) writeB(B_lds + ((q + 1) & 1) * BBUF_ELEMS);
        __syncthreads();
        if (q + 2 < TW) issue(q + 2);
    }

    // ---- epilogue: lane owns (b_out = mt*16+fq*4+r, o = nt*16+fr)
    const int o = nt * 16 + fr;
    #pragma unroll
    for (int r = 0; r < 4; ++r) {
        float* dst = out + ((size_t)((mt * 16 + fq * 4 + r) * OUTC + o)) * POUT
                         + (size_t)oh * OWD + ow0;
        #pragma unroll
        for (int j = 0; j < TW / 2; ++j) {
            f32x2 v = { acc[2 * j][r], acc[2 * j + 1][r] };
            *(f32x2*)(dst + 2 * j) = v;
        }
    }
}

__global__ __launch_bounds__(512, 4) void localconv_kernel(
    const float* __restrict__ inp,
    const float* __restrict__ wgt,
    float* __restrict__ out)
{
    extern __shared__ unsigned short smem[];
    unsigned short* Araw  = smem;
    unsigned short* B_lds = smem + AR_ELEMS;

    // chunked XCD swizzle: 496 = 8*62; XCD x gets contiguous l in [62x, 62x+62)
    const int l   = (blockIdx.x & 7) * 62 + (blockIdx.x >> 3);
    const int oh  = l >> 3;
    const int owt = l & 7;

    if (owt < 7) conv_body<8>(inp, wgt, out, oh, owt * 8, Araw, B_lds);
    else         conv_body<6>(inp, wgt, out, oh, 56, Araw, B_lds);
}

extern "C" void kernel_launch(void* const* d_in, const int* in_sizes, int n_in,
                              void* d_out, int out_size, void* d_ws, size_t ws_size,
                              hipStream_t stream) {
    const float* inp = (const float*)d_in[0];
    const float* wgt = (const float*)d_in[1];
    float* out = (float*)d_out;
    hipFuncSetAttribute((const void*)localconv_kernel,
                        hipFuncAttributeMaxDynamicSharedMemorySize, SMEM_BYTES);
    localconv_kernel<<<dim3(62 * 8), 512, SMEM_BYTES, stream>>>(inp, wgt, out);
}